// Round 1
// baseline (184.920 us; speedup 1.0000x reference)
//
#include <hip/hip_runtime.h>
#include <math.h>

// Elastic transform: [32,256,1024,3] fp32, 3x3 control grid displacement.
// Pipeline:
//   k_disp      : dense dy/dx fields [256,1024] from 3x3 control points
//   k_prefilt_h : cubic spline prefilter along H (37-tap mirror FIR == exact
//                 inverse collocation, g[k] = sqrt(3) * z^|k|, z = sqrt(3)-2)
//   k_prefilt_w : same along W, IN PLACE on coef (row fully staged in LDS)
//   k_sample    : 4x4 cubic B-spline gather at displaced coords, clamp, clip

#define H_ 256
#define W_ 1024
#define B_ 32
#define C_ 3
#define RAD 18               // |z|^18 ~ 5e-11 -> far below 2e-2 tolerance
#define ROWF 3072            // W_*C_ floats per (b,h) row

__device__ __forceinline__ float b3f(float t) {
    float a = fabsf(t);
    if (a < 1.0f) return (4.0f - 6.0f * a * a + 3.0f * a * a * a) * (1.0f / 6.0f);
    if (a < 2.0f) { float s = 2.0f - a; return s * s * s * (1.0f / 6.0f); }
    return 0.0f;
}

__device__ __forceinline__ float clamp01(float v) {
    return fminf(fmaxf(v, 0.0f), 1.0f);
}

// cubic B-spline basis row for P=3 control points, mirror folding (m=4)
__device__ __forceinline__ void basis3(int i, int n, float& w0, float& w1, float& w2) {
    float u = (float)i * 2.0f / (float)(n - 1);
    int base = (int)floorf(u);
    w0 = w1 = w2 = 0.0f;
#pragma unroll
    for (int k = -1; k < 3; ++k) {
        int id = base + k;
        float bw = b3f(u - (float)id);
        int j = id < 0 ? -id : id;
        j &= 3;
        if (j == 3) j = 1;           // min(j, 4-j)
        if (j == 0) w0 += bw; else if (j == 1) w1 += bw; else w2 += bw;
    }
}

// ---------------- kernel 0: displacement fields ----------------
__global__ __launch_bounds__(256) void k_disp(const float* __restrict__ disp,
                                              float* __restrict__ dyp,
                                              float* __restrict__ dxp) {
    int idx = blockIdx.x * 256 + threadIdx.x;   // 0..262143
    int h = idx >> 10, w = idx & 1023;

    // A3^{-1} is exact in binary fp
    const float A[3][3] = {{1.75f, -1.0f, 0.25f},
                           {-0.5f,  2.0f, -0.5f},
                           {0.25f, -1.0f, 1.75f}};
    float Cy[3][3], Cx[3][3];
#pragma unroll
    for (int i = 0; i < 3; ++i) {
#pragma unroll
        for (int j = 0; j < 3; ++j) {
            float ty = 0.f, tx = 0.f;
#pragma unroll
            for (int k = 0; k < 3; ++k) {
                ty += A[i][k] * (5.0f * disp[k * 3 + j]);
                tx += A[i][k] * (5.0f * disp[9 + k * 3 + j]);
            }
            Cy[i][j] = ty; Cx[i][j] = tx;   // temp = A * D
        }
    }
    // C = temp * A^T
    float Cy2[3][3], Cx2[3][3];
#pragma unroll
    for (int i = 0; i < 3; ++i) {
#pragma unroll
        for (int j = 0; j < 3; ++j) {
            float ty = 0.f, tx = 0.f;
#pragma unroll
            for (int k = 0; k < 3; ++k) {
                ty += Cy[i][k] * A[j][k];
                tx += Cx[i][k] * A[j][k];
            }
            Cy2[i][j] = ty; Cx2[i][j] = tx;
        }
    }

    float rh0, rh1, rh2, rw0, rw1, rw2;
    basis3(h, H_, rh0, rh1, rh2);
    basis3(w, W_, rw0, rw1, rw2);
    float rh[3] = {rh0, rh1, rh2}, rw[3] = {rw0, rw1, rw2};

    float dy = 0.f, dx = 0.f;
#pragma unroll
    for (int i = 0; i < 3; ++i)
#pragma unroll
        for (int j = 0; j < 3; ++j) {
            dy += rh[i] * Cy2[i][j] * rw[j];
            dx += rh[i] * Cx2[i][j] * rw[j];
        }
    dyp[idx] = dy;
    dxp[idx] = dx;
}

// ---------------- kernel 1: prefilter along H ----------------
// block: (chunk of 64 floats of a row) x (batch). LDS holds all 256 rows.
__global__ __launch_bounds__(256) void k_prefilt_h(const float* __restrict__ x,
                                                   float* __restrict__ coef) {
    __shared__ float tile[H_ * 64];   // 64 KiB exactly
    const int chunk = blockIdx.x;     // 0..47
    const int b = blockIdx.y;
    const int tid = threadIdx.x;

    const float* src = x + (size_t)b * H_ * ROWF + chunk * 64;
#pragma unroll
    for (int it = 0; it < 16; ++it) {
        int idx = tid + it * 256;          // 0..4095
        int r = idx >> 4, seg = idx & 15;
        *(float4*)(tile + r * 64 + seg * 4) =
            *(const float4*)(src + (size_t)r * ROWF + seg * 4);
    }
    __syncthreads();

    float g[RAD + 1];
    g[0] = 1.7320508075688773f;
#pragma unroll
    for (int k = 1; k <= RAD; ++k) g[k] = g[k - 1] * (-0.26794919243112270647f);

    const int cg = tid & 15;        // float4 column group
    const int prow = tid >> 4;      // 0..15
    const int p0 = prow * 16;

    float acc[16][4];
#pragma unroll
    for (int j = 0; j < 16; ++j) {
        acc[j][0] = 0.f; acc[j][1] = 0.f; acc[j][2] = 0.f; acc[j][3] = 0.f;
    }

#pragma unroll
    for (int r = 0; r < 16 + 2 * RAD; ++r) {   // 52 rows
        int hh = p0 - RAD + r;
        int m1 = hh < 0 ? -hh : hh;
        int m2 = 2 * (H_ - 1) - hh;            // 510 - hh
        int mp = m1 < m2 ? m1 : m2;
        float4 v = *(const float4*)(tile + mp * 64 + cg * 4);
#pragma unroll
        for (int j = 0; j < 16; ++j) {
            const int d = r - RAD - j;         // == tap k, compile-time
            if (d >= -RAD && d <= RAD) {
                const float wgt = g[d < 0 ? -d : d];
                acc[j][0] += wgt * v.x;
                acc[j][1] += wgt * v.y;
                acc[j][2] += wgt * v.z;
                acc[j][3] += wgt * v.w;
            }
        }
    }

    float* dst = coef + (size_t)b * H_ * ROWF + chunk * 64 + cg * 4;
#pragma unroll
    for (int j = 0; j < 16; ++j) {
        float4 o;
        o.x = acc[j][0]; o.y = acc[j][1]; o.z = acc[j][2]; o.w = acc[j][3];
        *(float4*)(dst + (size_t)(p0 + j) * ROWF) = o;
    }
}

// ---------------- kernel 2: prefilter along W (in place) ----------------
// one block per (b,p) row. Row deinterleaved into 3 channel planes with
// mirror halos so every tap read is an aligned float4.
#define PLN 1064                    // 18 + 1024 + 18, padded to /4
__global__ __launch_bounds__(256) void k_prefilt_w(float* __restrict__ coef) {
    __shared__ float pl[3 * PLN];   // ~12.5 KiB
    const int bp = blockIdx.x;      // b*256 + p
    const int t = threadIdx.x;
    float* row = coef + (size_t)bp * ROWF;

    // stage + deinterleave: thread t owns flat floats 12t .. 12t+11
    {
        float4 v0 = *(const float4*)(row + 12 * t);
        float4 v1 = *(const float4*)(row + 12 * t + 4);
        float4 v2 = *(const float4*)(row + 12 * t + 8);
        float vals[12] = {v0.x, v0.y, v0.z, v0.w,
                          v1.x, v1.y, v1.z, v1.w,
                          v2.x, v2.y, v2.z, v2.w};
        const int q0 = 4 * t;
#pragma unroll
        for (int e = 0; e < 12; ++e) {
            pl[(e % 3) * PLN + RAD + q0 + e / 3] = vals[e];   // all compile-time e
        }
    }
    __syncthreads();

    // mirror halos: left q=-1..-18 -> q'=1..18 ; right q=1024+r -> q'=1022-r
    if (t < 108) {                   // 3 planes * 36 halo entries
        int c = t / 36, i2 = t % 36;
        float* p = pl + c * PLN;
        if (i2 < 18) p[i2] = p[36 - i2];
        else { int r2 = i2 - 18; p[1042 + r2] = p[1040 - r2]; }
    }
    __syncthreads();

    float g[RAD + 1];
    g[0] = 1.7320508075688773f;
#pragma unroll
    for (int k = 1; k <= RAD; ++k) g[k] = g[k - 1] * (-0.26794919243112270647f);

    float acc[3][4];
#pragma unroll
    for (int c = 0; c < 3; ++c) { acc[c][0] = acc[c][1] = acc[c][2] = acc[c][3] = 0.f; }

#pragma unroll
    for (int c = 0; c < 3; ++c) {
        const float* p = pl + c * PLN + 4 * t;   // phys index of q0-18
        float w[40];
#pragma unroll
        for (int i = 0; i < 10; ++i) {
            float4 v = *(const float4*)(p + 4 * i);
            w[4 * i] = v.x; w[4 * i + 1] = v.y; w[4 * i + 2] = v.z; w[4 * i + 3] = v.w;
        }
#pragma unroll
        for (int jq = 0; jq < 4; ++jq) {
#pragma unroll
            for (int k = -RAD; k <= RAD; ++k) {
                acc[c][jq] += g[k < 0 ? -k : k] * w[jq + RAD + k];
            }
        }
    }

    float outv[12];
#pragma unroll
    for (int e = 0; e < 12; ++e) outv[e] = acc[e % 3][e / 3];
    float4 s0, s1, s2;
    s0.x = outv[0]; s0.y = outv[1]; s0.z = outv[2]; s0.w = outv[3];
    s1.x = outv[4]; s1.y = outv[5]; s1.z = outv[6]; s1.w = outv[7];
    s2.x = outv[8]; s2.y = outv[9]; s2.z = outv[10]; s2.w = outv[11];
    *(float4*)(row + 12 * t) = s0;
    *(float4*)(row + 12 * t + 4) = s1;
    *(float4*)(row + 12 * t + 8) = s2;
}

// ---------------- kernel 3: 4x4 cubic gather ----------------
__global__ __launch_bounds__(256) void k_sample(const float* __restrict__ coef,
                                                const float* __restrict__ dyp,
                                                const float* __restrict__ dxp,
                                                float* __restrict__ out) {
    int gidx = blockIdx.x * 256 + threadIdx.x;   // 0 .. 32*256*1024-1
    int b = gidx >> 18;
    int hw = gidx & 262143;
    int h = hw >> 10, w = hw & 1023;

    float cy = (float)h + dyp[hw];
    float cx = (float)w + dxp[hw];
    float byf = floorf(cy), bxf = floorf(cx);
    int by = (int)byf, bx = (int)bxf;
    float fy = cy - byf, fx = cx - bxf;

    float wy[4], wx[4];
    wy[0] = b3f(fy + 1.f); wy[1] = b3f(fy); wy[2] = b3f(fy - 1.f); wy[3] = b3f(fy - 2.f);
    wx[0] = b3f(fx + 1.f); wx[1] = b3f(fx); wx[2] = b3f(fx - 1.f); wx[3] = b3f(fx - 2.f);

    int iy[4], ix[4];
#pragma unroll
    for (int k = 0; k < 4; ++k) {
        iy[k] = min(max(by + k - 1, 0), H_ - 1);
        ix[k] = min(max(bx + k - 1, 0), W_ - 1);
    }

    float a0 = 0.f, a1 = 0.f, a2 = 0.f;
    const float* base_b = coef + (size_t)b * H_ * ROWF;
#pragma unroll
    for (int ky = 0; ky < 4; ++ky) {
        const float* rowp = base_b + (size_t)iy[ky] * ROWF;
#pragma unroll
        for (int kx = 0; kx < 4; ++kx) {
            float wgt = wy[ky] * wx[kx];
            const float* p = rowp + ix[kx] * 3;
            a0 += wgt * p[0];
            a1 += wgt * p[1];
            a2 += wgt * p[2];
        }
    }

    float* o = out + (size_t)gidx * 3;
    o[0] = clamp01(a0);
    o[1] = clamp01(a1);
    o[2] = clamp01(a2);
}

extern "C" void kernel_launch(void* const* d_in, const int* in_sizes, int n_in,
                              void* d_out, int out_size, void* d_ws, size_t ws_size,
                              hipStream_t stream) {
    const float* x = (const float*)d_in[0];      // [32,256,1024,3]
    const float* disp = (const float*)d_in[1];   // [2,3,3]
    float* out = (float*)d_out;

    char* ws = (char*)d_ws;
    float* coef = (float*)ws;                                  // 100,663,296 B
    float* dy = (float*)(ws + 100663296ull);                   // 1 MiB
    float* dx = (float*)(ws + 100663296ull + 1048576ull);      // 1 MiB
    // total ws needed: ~98.1 MiB

    k_disp<<<dim3((H_ * W_) / 256), dim3(256), 0, stream>>>(disp, dy, dx);

    dim3 g1(ROWF / 64, B_);
    k_prefilt_h<<<g1, dim3(256), 0, stream>>>(x, coef);

    k_prefilt_w<<<dim3(B_ * H_), dim3(256), 0, stream>>>(coef);

    k_sample<<<dim3((B_ * H_ * W_) / 256), dim3(256), 0, stream>>>(coef, dy, dx, out);
}